// Round 10
// baseline (204.922 us; speedup 1.0000x reference)
//
#include <hip/hip_runtime.h>

#define IMG 224
#define PATCHSZ 16
#define CHN 3
#define DDIM 768
#define ROWN 14
#define NPATCH 196
#define PDIM 768
#define BATCH 32

#define DTILE 256                 // d-cols per block (3 blocks per patch)
#define NDBLK (DDIM / DTILE)      // 3
#define KSUB 16                   // k rows per step (W and P)
#define NSUB (PDIM / KSUB)        // 48

// Kernel 1: x[32][3][224][224] -> P[196][32][768]
__global__ void extract_patches_kernel(const float* __restrict__ x,
                                       float* __restrict__ P) {
    int i = blockIdx.x * blockDim.x + threadIdx.x;
    if (i >= NPATCH * BATCH * PDIM) return;
    int k  = i % PDIM;
    int nb = i / PDIM;
    int b  = nb % BATCH;
    int n  = nb / BATCH;
    int ch = k >> 8;
    int py = (k >> 4) & 15;
    int px = k & 15;
    int r = n / ROWN, c = n % ROWN;
    P[i] = x[(((size_t)b * CHN + ch) * IMG + r * PATCHSZ + py) * IMG
             + c * PATCHSZ + px];
}

#define ACC_ROW(i, pv, wj)                                                   \
    acc[i][0] = fmaf(pv, wj.x, acc[i][0]);                                   \
    acc[i][1] = fmaf(pv, wj.y, acc[i][1]);                                   \
    acc[i][2] = fmaf(pv, wj.z, acc[i][2]);                                   \
    acc[i][3] = fmaf(pv, wj.w, acc[i][3]);

// per patch n: out[:,n,d0:d0+256] = P[n] (32x768) * W[n][:,d0:d0+256] + bias
// grid 196*3, block 256; thread tile 8 batches x 4 d-cols.
// ALL staging via global_load_lds into 3-slot rings; counted vmcnt
// (never drains to 0 in the main loop): wait batch v with v+1, v+2 in flight.
__global__ __launch_bounds__(256, 2) void patch_gemm_kernel(
    const float* __restrict__ P,    // [196][32][768]
    const float* __restrict__ W,    // [196][768][768]
    const float* __restrict__ bias, // [196][768]
    float* __restrict__ out)        // [32][196][768]
{
    __shared__ __align__(16) float wt[3][KSUB][DTILE]; // 48 KB W ring
    __shared__ __align__(16) float pt[3][BATCH * KSUB]; // 6 KB P ring, [b][k]

    const int blk  = blockIdx.x;
    const int n    = blk / NDBLK;
    const int dblk = blk % NDBLK;
    const int tid  = threadIdx.x;
    const int ln   = tid & 63;      // lane; d-quad index (64 x 4 = 256 cols)
    const int wv   = tid >> 6;      // wave 0..3
    const int b0   = wv * 8;        // batch group per wave
    const int d    = dblk * DTILE + ln * 4;

    const float* Wn0 = W + (size_t)n * PDIM * DDIM + dblk * DTILE;
    const float* Pn  = P + (size_t)n * BATCH * PDIM;

    float acc[8][4];
#pragma unroll
    for (int i = 0; i < 8; ++i)
#pragma unroll
        for (int j = 0; j < 4; ++j) acc[i][j] = 0.f;

    // one batch = W sub v (16 rows x 256 cols, 16 KB; 4 loads/wave)
    //           + P sub v (32 b x 16 k, 2 KB; 1 load each for waves 0,1).
    // P dest is lane-linear: lane l -> pt + wv*256 + l*4 floats.
    auto issueBatch = [&](int v) {
        const int slot = v % 3;
        const float* wsrc = Wn0 + (size_t)v * KSUB * DDIM;
        float* wdst = &wt[slot][0][0];
#pragma unroll
        for (int j = 0; j < 4; ++j) {
            const int row = wv * 4 + j;
            __builtin_amdgcn_global_load_lds(
                (const __attribute__((address_space(1))) unsigned int*)
                    (wsrc + (size_t)row * DDIM + ln * 4),
                (__attribute__((address_space(3))) unsigned int*)
                    (wdst + row * DTILE + ln * 4),
                16, 0, 0);
        }
        if (wv < 2) {
            const int b  = wv * 16 + (ln >> 2);   // 32 rows over 2 waves
            const int ko = (ln & 3) * 4;          // 4 lanes x 4 floats = 16 k
            __builtin_amdgcn_global_load_lds(
                (const __attribute__((address_space(1))) unsigned int*)
                    (Pn + (size_t)b * PDIM + v * KSUB + ko),
                (__attribute__((address_space(3))) unsigned int*)
                    (&pt[slot][0] + b * KSUB + ko),
                16, 0, 0);
        }
    };

    issueBatch(0);
    issueBatch(1);

#pragma unroll 1
    for (int v = 0; v < NSUB; ++v) {
        // wait: batch v landed; batches v+1 (and v+2 after issue) in flight.
        if (v == NSUB - 1) {
            asm volatile("s_waitcnt vmcnt(0)" ::: "memory");
        } else if (wv < 2) {
            asm volatile("s_waitcnt vmcnt(5)" ::: "memory");  // newer: 4W+1P
        } else {
            asm volatile("s_waitcnt vmcnt(4)" ::: "memory");  // newer: 4W
        }
        __builtin_amdgcn_s_barrier();
        __builtin_amdgcn_sched_barrier(0);

        if (v + 2 < NSUB) issueBatch(v + 2);

        const int slot = v % 3;
        const float* wbuf = &wt[slot][0][0] + ln * 4;
        const float* pbuf = &pt[slot][0] + b0 * KSUB;

#pragma unroll 4
        for (int kk = 0; kk < KSUB; ++kk) {
            float4 w = *reinterpret_cast<const float4*>(wbuf + kk * DTILE);
            // 8 wave-uniform broadcast b32 reads (conflict-free)
            float p0 = pbuf[0 * KSUB + kk];
            float p1 = pbuf[1 * KSUB + kk];
            float p2 = pbuf[2 * KSUB + kk];
            float p3 = pbuf[3 * KSUB + kk];
            float p4 = pbuf[4 * KSUB + kk];
            float p5 = pbuf[5 * KSUB + kk];
            float p6 = pbuf[6 * KSUB + kk];
            float p7 = pbuf[7 * KSUB + kk];
            ACC_ROW(0, p0, w) ACC_ROW(1, p1, w)
            ACC_ROW(2, p2, w) ACC_ROW(3, p3, w)
            ACC_ROW(4, p4, w) ACC_ROW(5, p5, w)
            ACC_ROW(6, p6, w) ACC_ROW(7, p7, w)
        }
    }

    float4 bv = *reinterpret_cast<const float4*>(bias + (size_t)n * DDIM + d);
#pragma unroll
    for (int i = 0; i < 8; ++i) {
        const int b = b0 + i;
        float4 o;
        o.x = acc[i][0] + bv.x;
        o.y = acc[i][1] + bv.y;
        o.z = acc[i][2] + bv.z;
        o.w = acc[i][3] + bv.w;
        *reinterpret_cast<float4*>(out + ((size_t)b * NPATCH + n) * DDIM + d) = o;
    }
}

extern "C" void kernel_launch(void* const* d_in, const int* in_sizes, int n_in,
                              void* d_out, int out_size, void* d_ws, size_t ws_size,
                              hipStream_t stream) {
    const float* x    = (const float*)d_in[0];
    const float* W    = (const float*)d_in[1];
    const float* bias = (const float*)d_in[2];
    float* out = (float*)d_out;
    float* P   = (float*)d_ws;   // 196*32*768*4 = 19.3 MB

    int total = NPATCH * BATCH * PDIM;
    extract_patches_kernel<<<(total + 255) / 256, 256, 0, stream>>>(x, P);
    patch_gemm_kernel<<<NPATCH * NDBLK, 256, 0, stream>>>(P, W, bias, out);
}